// Round 4
// baseline (439.657 us; speedup 1.0000x reference)
//
#include <hip/hip_runtime.h>
#include <hip/hip_bf16.h>

// Problem constants: B=4, F=8, C=16, H=256, W=256, K=64
#define NB 4
#define NF 8
#define NC 16
#define NK 64
#define HW 65536              // H*W
#define NBF 32                // B*F
#define BPF 64                // blocks per frame (4x round-3 for occupancy)
#define PPB (HW / BPF)        // 1024 pixels per block
#define PPW (PPB / 4)         // 256 pixels per wave
#define STEPS (PPW / 32)      // 8 K-steps of 32 pixels

typedef __attribute__((ext_vector_type(8))) short bf16x8;  // MFMA A/B frag (8 bf16)
typedef __attribute__((ext_vector_type(4))) float f32x4;   // MFMA C/D frag

__global__ __launch_bounds__(256) void zero_kernel(float* __restrict__ p, int n) {
    int i = blockIdx.x * blockDim.x + threadIdx.x;
    if (i < n) p[i] = 0.0f;
}

__device__ __forceinline__ short f32_to_bf16_bits(float x) {
    union { float f; unsigned u; } v; v.f = x;
    unsigned r = v.u + 0x7FFFu + ((v.u >> 16) & 1u);   // round-nearest-even
    return (short)(r >> 16);
}

// Segment-sum via one-hot MFMA. Per wave: 32-pixel K-steps.
//   A (16x32, bf16): onehot[k - 16t][p]; rows = lane&15, k-slots mirrored with B.
//   B (32x16, bf16): data[p][c]; cols = lane&15 (channel plane), 8 px/lane.
//   C/D layout (verified m89/m91): col = lane&15, row = (lane>>4)*4 + reg.
__global__ __launch_bounds__(256, 8) void accum_mfma(const float* __restrict__ E,
                                                     const int* __restrict__ T,
                                                     float* __restrict__ gsum,   // [bf][k][c]
                                                     float* __restrict__ gcnt) { // [bf][k]
    const int tid = threadIdx.x;
    const int wv  = tid >> 6;
    const int l   = tid & 63;
    const int col = l & 15;    // channel (B/C col) AND A row-within-tile
    const int grp = l >> 4;    // pixel-slot group

    const int bf    = blockIdx.x / BPF;
    const int chunk = blockIdx.x % BPF;
    const int base  = chunk * PPB + wv * PPW + grp * 8;

    const int*   Tp = T + (size_t)bf * HW + base;
    const float* Ep = E + ((size_t)bf * NC + col) * HW + base;

    f32x4 accS[4], accC[4];
    #pragma unroll
    for (int t = 0; t < 4; ++t) { accS[t] = (f32x4){0,0,0,0}; accC[t] = (f32x4){0,0,0,0}; }

    // Constant ones-fragment: B[p][0] = 1.0 for all p -> counts land in col 0.
    bf16x8 bOnes;
    {
        const short ov = (col == 0) ? (short)0x3F80 : (short)0;
        #pragma unroll
        for (int j = 0; j < 8; ++j) bOnes[j] = ov;
    }

    #pragma unroll 2
    for (int s = 0; s < STEPS; ++s) {
        const int off = s * 32;
        const int4   i0 = *reinterpret_cast<const int4*>(Tp + off);
        const int4   i1 = *reinterpret_cast<const int4*>(Tp + off + 4);
        const float4 d0 = *reinterpret_cast<const float4*>(Ep + off);
        const float4 d1 = *reinterpret_cast<const float4*>(Ep + off + 4);

        const int   idv[8] = {i0.x, i0.y, i0.z, i0.w, i1.x, i1.y, i1.z, i1.w};
        const float dv[8]  = {d0.x, d0.y, d0.z, d0.w, d1.x, d1.y, d1.z, d1.w};

        bf16x8 bF;
        #pragma unroll
        for (int j = 0; j < 8; ++j) bF[j] = f32_to_bf16_bits(dv[j]);

        #pragma unroll
        for (int t = 0; t < 4; ++t) {
            const int ktar = t * 16 + col;
            bf16x8 aT;
            #pragma unroll
            for (int j = 0; j < 8; ++j) aT[j] = (idv[j] == ktar) ? (short)0x3F80 : (short)0;
            accS[t] = __builtin_amdgcn_mfma_f32_16x16x32_bf16(aT, bF,    accS[t], 0, 0, 0);
            accC[t] = __builtin_amdgcn_mfma_f32_16x16x32_bf16(aT, bOnes, accC[t], 0, 0, 0);
        }
    }

    // Cross-wave reduce in LDS, then one global atomic per output element.
    __shared__ float lsum[4][NK][NC];   // 16 KiB
    __shared__ float lcnt[4][NK];       // 1 KiB
    #pragma unroll
    for (int t = 0; t < 4; ++t) {
        #pragma unroll
        for (int j = 0; j < 4; ++j) {
            const int k = t * 16 + grp * 4 + j;   // C/D row mapping (m89)
            lsum[wv][k][col] = accS[t][j];
            if (col == 0) lcnt[wv][k] = accC[t][j];
        }
    }
    __syncthreads();

    float* gs = gsum + (size_t)bf * NK * NC;
    const float* lp = &lsum[0][0][0];
    for (int i = tid; i < NK * NC; i += 256) {
        atomicAdd(&gs[i], lp[i] + lp[NK*NC + i] + lp[2*NK*NC + i] + lp[3*NK*NC + i]);
    }
    if (tid < NK) {
        atomicAdd(&gcnt[(size_t)bf * NK + tid],
                  lcnt[0][tid] + lcnt[1][tid] + lcnt[2][tid] + lcnt[3][tid]);
    }
}

// Single block: 4*7*64 = 1792 (b, f-pair, k) combos, reduce to scalar.
__global__ __launch_bounds__(256) void finish_kernel(const float* __restrict__ gsum,
                                                     const float* __restrict__ gcnt,
                                                     float* __restrict__ out) {
    float total = 0.0f, nv = 0.0f;
    for (int idx = threadIdx.x; idx < NB * (NF - 1) * NK; idx += 256) {
        const int k = idx & 63;
        const int bfr = idx >> 6;
        const int b = bfr / (NF - 1);
        const int f = bfr % (NF - 1);
        const int bf0 = b * NF + f;
        if (k == 0) continue;
        const float c0 = gcnt[bf0 * NK + k];
        const float c1 = gcnt[(bf0 + 1) * NK + k];
        if (c0 > 0.0f && c1 > 0.0f) {
            const float r0 = 1.0f / c0, r1 = 1.0f / c1;
            float d = 0.0f;
            #pragma unroll
            for (int c = 0; c < NC; ++c) {
                const float m0 = gsum[(size_t)bf0 * (NK * NC) + k * NC + c] * r0;
                const float m1 = gsum[(size_t)(bf0 + 1) * (NK * NC) + k * NC + c] * r1;
                const float df = m0 - m1;
                d += df * df;
            }
            total += d;
            nv += 1.0f;
        }
    }
    const int lane = threadIdx.x & 63;
    const int wvi  = threadIdx.x >> 6;
    #pragma unroll
    for (int off = 32; off > 0; off >>= 1) {
        total += __shfl_down(total, off, 64);
        nv    += __shfl_down(nv, off, 64);
    }
    __shared__ float sT[4], sN[4];
    if (lane == 0) { sT[wvi] = total; sN[wvi] = nv; }
    __syncthreads();
    if (threadIdx.x == 0) {
        const float t = sT[0] + sT[1] + sT[2] + sT[3];
        const float n = sN[0] + sN[1] + sN[2] + sN[3];
        out[0] = (n > 0.0f) ? (t / n) : 0.0f;
    }
}

extern "C" void kernel_launch(void* const* d_in, const int* in_sizes, int n_in,
                              void* d_out, int out_size, void* d_ws, size_t ws_size,
                              hipStream_t stream) {
    const float* E = (const float*)d_in[0];   // embeddings (4,8,16,256,256) f32
    const int*   T = (const int*)d_in[1];     // track_ids  (4,8,1,256,256) i32
    float* out = (float*)d_out;

    float* gsum = (float*)d_ws;               // [32][64][16]
    float* gcnt = gsum + NBF * NK * NC;       // [32][64]
    const int ntot = NBF * NK * NC + NBF * NK;

    zero_kernel<<<(ntot + 255) / 256, 256, 0, stream>>>(gsum, ntot);
    accum_mfma<<<NBF * BPF, 256, 0, stream>>>(E, T, gsum, gcnt);
    finish_kernel<<<1, 256, 0, stream>>>(gsum, gcnt, out);
}

// Round 5
// 213.940 us; speedup vs baseline: 2.0551x; 2.0551x over previous
//
#include <hip/hip_runtime.h>
#include <hip/hip_bf16.h>

// Problem constants: B=4, F=8, C=16, H=256, W=256, K=64
#define NB 4
#define NF 8
#define NC 16
#define NK 64
#define HW 65536              // H*W
#define NBF 32                // B*F
#define BPF 64                // blocks per frame (2048 blocks = 8/CU)
#define PPB (HW / BPF)        // 1024 pixels per block
#define PPW (PPB / 4)         // 256 pixels per wave
#define STEPS (PPW / 32)      // 8 K-steps of 32 pixels

typedef __attribute__((ext_vector_type(8))) short bf16x8;  // MFMA A/B frag (8 bf16)
typedef __attribute__((ext_vector_type(4))) float f32x4;   // MFMA C/D frag

__global__ __launch_bounds__(256) void zero_kernel(float* __restrict__ p, int n) {
    int i = blockIdx.x * blockDim.x + threadIdx.x;
    if (i < n) p[i] = 0.0f;
}

__device__ __forceinline__ short f32_to_bf16_bits(float x) {
    union { float f; unsigned u; } v; v.f = x;
    unsigned r = v.u + 0x7FFFu + ((v.u >> 16) & 1u);   // round-nearest-even
    return (short)(r >> 16);
}

// Segment-sum via one-hot MFMA. Per wave: 32-pixel K-steps.
//   A (16x32, bf16): onehot[k - 16t][p]; rows = lane&15, k-slots mirrored with B.
//   B (32x16, bf16): data[p][c]; cols = lane&15 (channel plane), 8 px/lane.
//   C/D layout (verified m89/m91): col = lane&15, row = (lane>>4)*4 + reg.
// NOTE: plain __launch_bounds__(256). Adding a min-waves-per-EU of 8 (round 4)
// caps the unified VGPR+AGPR budget at 64/wave -> inner-loop scratch spills
// (~1 GB traffic, 4x slowdown). 36 VGPR compiles under the 64-reg threshold,
// so 8 waves/SIMD occupancy is still available without the constraint.
__global__ __launch_bounds__(256) void accum_mfma(const float* __restrict__ E,
                                                  const int* __restrict__ T,
                                                  float* __restrict__ gsum,   // [bf][k][c]
                                                  float* __restrict__ gcnt) { // [bf][k]
    const int tid = threadIdx.x;
    const int wv  = tid >> 6;
    const int l   = tid & 63;
    const int col = l & 15;    // channel (B/C col) AND A row-within-tile
    const int grp = l >> 4;    // pixel-slot group

    const int bf    = blockIdx.x / BPF;
    const int chunk = blockIdx.x % BPF;
    const int base  = chunk * PPB + wv * PPW + grp * 8;

    const int*   Tp = T + (size_t)bf * HW + base;
    const float* Ep = E + ((size_t)bf * NC + col) * HW + base;

    f32x4 accS[4], accC[4];
    #pragma unroll
    for (int t = 0; t < 4; ++t) { accS[t] = (f32x4){0,0,0,0}; accC[t] = (f32x4){0,0,0,0}; }

    // Constant ones-fragment: B[p][0] = 1.0 for all p -> counts land in col 0.
    bf16x8 bOnes;
    {
        const short ov = (col == 0) ? (short)0x3F80 : (short)0;
        #pragma unroll
        for (int j = 0; j < 8; ++j) bOnes[j] = ov;
    }

    for (int s = 0; s < STEPS; ++s) {
        const int off = s * 32;
        const int4   i0 = *reinterpret_cast<const int4*>(Tp + off);
        const int4   i1 = *reinterpret_cast<const int4*>(Tp + off + 4);
        const float4 d0 = *reinterpret_cast<const float4*>(Ep + off);
        const float4 d1 = *reinterpret_cast<const float4*>(Ep + off + 4);

        const int   idv[8] = {i0.x, i0.y, i0.z, i0.w, i1.x, i1.y, i1.z, i1.w};
        const float dv[8]  = {d0.x, d0.y, d0.z, d0.w, d1.x, d1.y, d1.z, d1.w};

        bf16x8 bF;
        #pragma unroll
        for (int j = 0; j < 8; ++j) bF[j] = f32_to_bf16_bits(dv[j]);

        #pragma unroll
        for (int t = 0; t < 4; ++t) {
            const int ktar = t * 16 + col;
            bf16x8 aT;
            #pragma unroll
            for (int j = 0; j < 8; ++j) aT[j] = (idv[j] == ktar) ? (short)0x3F80 : (short)0;
            accS[t] = __builtin_amdgcn_mfma_f32_16x16x32_bf16(aT, bF,    accS[t], 0, 0, 0);
            accC[t] = __builtin_amdgcn_mfma_f32_16x16x32_bf16(aT, bOnes, accC[t], 0, 0, 0);
        }
    }

    // Cross-wave reduce in LDS, then one global atomic per output element.
    __shared__ float lsum[4][NK][NC];   // 16 KiB
    __shared__ float lcnt[4][NK];       // 1 KiB
    #pragma unroll
    for (int t = 0; t < 4; ++t) {
        #pragma unroll
        for (int j = 0; j < 4; ++j) {
            const int k = t * 16 + grp * 4 + j;   // C/D row mapping (m89)
            lsum[wv][k][col] = accS[t][j];
            if (col == 0) lcnt[wv][k] = accC[t][j];
        }
    }
    __syncthreads();

    float* gs = gsum + (size_t)bf * NK * NC;
    const float* lp = &lsum[0][0][0];
    for (int i = tid; i < NK * NC; i += 256) {
        atomicAdd(&gs[i], lp[i] + lp[NK*NC + i] + lp[2*NK*NC + i] + lp[3*NK*NC + i]);
    }
    if (tid < NK) {
        atomicAdd(&gcnt[(size_t)bf * NK + tid],
                  lcnt[0][tid] + lcnt[1][tid] + lcnt[2][tid] + lcnt[3][tid]);
    }
}

// Single block: 4*7*64 = 1792 (b, f-pair, k) combos, reduce to scalar.
__global__ __launch_bounds__(256) void finish_kernel(const float* __restrict__ gsum,
                                                     const float* __restrict__ gcnt,
                                                     float* __restrict__ out) {
    float total = 0.0f, nv = 0.0f;
    for (int idx = threadIdx.x; idx < NB * (NF - 1) * NK; idx += 256) {
        const int k = idx & 63;
        const int bfr = idx >> 6;
        const int b = bfr / (NF - 1);
        const int f = bfr % (NF - 1);
        const int bf0 = b * NF + f;
        if (k == 0) continue;
        const float c0 = gcnt[bf0 * NK + k];
        const float c1 = gcnt[(bf0 + 1) * NK + k];
        if (c0 > 0.0f && c1 > 0.0f) {
            const float r0 = 1.0f / c0, r1 = 1.0f / c1;
            float d = 0.0f;
            #pragma unroll
            for (int c = 0; c < NC; ++c) {
                const float m0 = gsum[(size_t)bf0 * (NK * NC) + k * NC + c] * r0;
                const float m1 = gsum[(size_t)(bf0 + 1) * (NK * NC) + k * NC + c] * r1;
                const float df = m0 - m1;
                d += df * df;
            }
            total += d;
            nv += 1.0f;
        }
    }
    const int lane = threadIdx.x & 63;
    const int wvi  = threadIdx.x >> 6;
    #pragma unroll
    for (int off = 32; off > 0; off >>= 1) {
        total += __shfl_down(total, off, 64);
        nv    += __shfl_down(nv, off, 64);
    }
    __shared__ float sT[4], sN[4];
    if (lane == 0) { sT[wvi] = total; sN[wvi] = nv; }
    __syncthreads();
    if (threadIdx.x == 0) {
        const float t = sT[0] + sT[1] + sT[2] + sT[3];
        const float n = sN[0] + sN[1] + sN[2] + sN[3];
        out[0] = (n > 0.0f) ? (t / n) : 0.0f;
    }
}

extern "C" void kernel_launch(void* const* d_in, const int* in_sizes, int n_in,
                              void* d_out, int out_size, void* d_ws, size_t ws_size,
                              hipStream_t stream) {
    const float* E = (const float*)d_in[0];   // embeddings (4,8,16,256,256) f32
    const int*   T = (const int*)d_in[1];     // track_ids  (4,8,1,256,256) i32
    float* out = (float*)d_out;

    float* gsum = (float*)d_ws;               // [32][64][16]
    float* gcnt = gsum + NBF * NK * NC;       // [32][64]
    const int ntot = NBF * NK * NC + NBF * NK;

    zero_kernel<<<(ntot + 255) / 256, 256, 0, stream>>>(gsum, ntot);
    accum_mfma<<<NBF * BPF, 256, 0, stream>>>(E, T, gsum, gcnt);
    finish_kernel<<<1, 256, 0, stream>>>(gsum, gcnt, out);
}

// Round 7
// 213.647 us; speedup vs baseline: 2.0579x; 1.0014x over previous
//
#include <hip/hip_runtime.h>
#include <hip/hip_bf16.h>

// Problem constants: B=4, F=8, C=16, H=256, W=256, K=64
#define NB 4
#define NF 8
#define NC 16
#define NK 64
#define HW 65536              // H*W
#define NBF 32                // B*F
#define BPF 64                // blocks per frame (2048 blocks)
#define PPB (HW / BPF)        // 1024 pixels per block
#define PPW (PPB / 4)         // 256 pixels per wave
#define STEPS (PPW / 32)      // 8 K-steps of 32 pixels
#define PARTSZ 1088           // per-block partial: 1024 sums + 64 counts

typedef __attribute__((ext_vector_type(8))) short bf16x8;  // MFMA A/B frag (8 bf16)
typedef __attribute__((ext_vector_type(4))) float f32x4;   // MFMA C/D frag

__device__ __forceinline__ short f32_to_bf16_bits(float x) {
    union { float f; unsigned u; } v; v.f = x;
    unsigned r = v.u + 0x7FFFu + ((v.u >> 16) & 1u);   // round-nearest-even
    return (short)(r >> 16);
}

// Segment-sum via one-hot MFMA. Per wave: 32-pixel K-steps.
//   A (16x32, bf16): onehot[k - 16t][p]; rows = lane&15, k-slots mirrored with B.
//   B (32x16, bf16): data[p][c]; cols = lane&15 (channel plane), 8 px/lane.
//   C/D layout (verified m89/m91): col = lane&15, row = (lane>>4)*4 + reg.
// Changes vs r5: (1) ids staged in LDS once per block (kills 16x-redundant
// broadcast global loads in the loop); (2) epilogue writes per-block partials
// with plain stores — NO global atomics; (3) unroll 2 for load pipelining.
// NOTE: no min-waves launch_bounds — the (256,8) cap caused scratch spills
// (r4: ~1 GB spill traffic).
__global__ __launch_bounds__(256) void accum_mfma(const float* __restrict__ E,
                                                  const int* __restrict__ T,
                                                  float* __restrict__ part) {  // [2048][PARTSZ]
    __shared__ int   sids[PPB];         // 4 KiB
    __shared__ float lsum[4][NK][NC];   // 16 KiB
    __shared__ float lcnt[4][NK];       // 1 KiB

    const int tid = threadIdx.x;
    const int wv  = tid >> 6;
    const int l   = tid & 63;
    const int col = l & 15;    // channel (B/C col) AND A row-within-tile
    const int grp = l >> 4;    // pixel-slot group

    const int bf    = blockIdx.x / BPF;
    const int chunk = blockIdx.x % BPF;

    // Stage this block's 1024 ids into LDS (one block-wide int4 load).
    *reinterpret_cast<int4*>(&sids[tid * 4]) =
        *reinterpret_cast<const int4*>(T + (size_t)bf * HW + chunk * PPB + tid * 4);
    __syncthreads();

    const int base = chunk * PPB + wv * PPW + grp * 8;
    const float* Ep = E + ((size_t)bf * NC + col) * HW + base;
    const int* sip = &sids[wv * PPW + grp * 8];

    f32x4 accS[4], accC[4];
    #pragma unroll
    for (int t = 0; t < 4; ++t) { accS[t] = (f32x4){0,0,0,0}; accC[t] = (f32x4){0,0,0,0}; }

    // Constant ones-fragment: B[p][0] = 1.0 for all p -> counts land in col 0.
    bf16x8 bOnes;
    {
        const short ov = (col == 0) ? (short)0x3F80 : (short)0;
        #pragma unroll
        for (int j = 0; j < 8; ++j) bOnes[j] = ov;
    }

    #pragma unroll 2
    for (int s = 0; s < STEPS; ++s) {
        const int off = s * 32;
        const int4   i0 = *reinterpret_cast<const int4*>(sip + off);      // LDS broadcast
        const int4   i1 = *reinterpret_cast<const int4*>(sip + off + 4);  // LDS broadcast
        const float4 d0 = *reinterpret_cast<const float4*>(Ep + off);
        const float4 d1 = *reinterpret_cast<const float4*>(Ep + off + 4);

        const int   idv[8] = {i0.x, i0.y, i0.z, i0.w, i1.x, i1.y, i1.z, i1.w};
        const float dv[8]  = {d0.x, d0.y, d0.z, d0.w, d1.x, d1.y, d1.z, d1.w};

        bf16x8 bF;
        #pragma unroll
        for (int j = 0; j < 8; ++j) bF[j] = f32_to_bf16_bits(dv[j]);

        #pragma unroll
        for (int t = 0; t < 4; ++t) {
            const int ktar = t * 16 + col;
            bf16x8 aT;
            #pragma unroll
            for (int j = 0; j < 8; ++j) aT[j] = (idv[j] == ktar) ? (short)0x3F80 : (short)0;
            accS[t] = __builtin_amdgcn_mfma_f32_16x16x32_bf16(aT, bF,    accS[t], 0, 0, 0);
            accC[t] = __builtin_amdgcn_mfma_f32_16x16x32_bf16(aT, bOnes, accC[t], 0, 0, 0);
        }
    }

    // Cross-wave reduce in LDS, then plain coalesced stores of block partials.
    #pragma unroll
    for (int t = 0; t < 4; ++t) {
        #pragma unroll
        for (int j = 0; j < 4; ++j) {
            const int k = t * 16 + grp * 4 + j;   // C/D row mapping (m89)
            lsum[wv][k][col] = accS[t][j];
            if (col == 0) lcnt[wv][k] = accC[t][j];
        }
    }
    __syncthreads();

    float* pp = part + (size_t)blockIdx.x * PARTSZ;
    const float* lp = &lsum[0][0][0];
    for (int i = tid; i < NK * NC; i += 256) {
        pp[i] = lp[i] + lp[NK*NC + i] + lp[2*NK*NC + i] + lp[3*NK*NC + i];
    }
    if (tid < NK) {
        pp[NK * NC + tid] = lcnt[0][tid] + lcnt[1][tid] + lcnt[2][tid] + lcnt[3][tid];
    }
}

// Sum the 64 block-partials per frame, fixed order, no atomics.
// Grid: 136 blocks x 256 threads = 34816 = 32768 sum-elems + 2048 cnt-elems.
__global__ __launch_bounds__(256) void reduce_kernel(const float* __restrict__ part,
                                                     float* __restrict__ gsum,   // [bf][k][c]
                                                     float* __restrict__ gcnt) { // [bf][k]
    const int e = blockIdx.x * 256 + threadIdx.x;
    if (e < NBF * NK * NC) {
        const int bf = e >> 10;          // / 1024
        const int i  = e & 1023;
        const float* p = part + (size_t)(bf * BPF) * PARTSZ + i;
        float s = 0.0f;
        #pragma unroll 8
        for (int blk = 0; blk < BPF; ++blk) s += p[(size_t)blk * PARTSZ];
        gsum[e] = s;
    } else {
        const int e2 = e - NBF * NK * NC;
        const int bf = e2 >> 6;
        const int k  = e2 & 63;
        const float* p = part + (size_t)(bf * BPF) * PARTSZ + NK * NC + k;
        float s = 0.0f;
        #pragma unroll 8
        for (int blk = 0; blk < BPF; ++blk) s += p[(size_t)blk * PARTSZ];
        gcnt[e2] = s;
    }
}

// Single block: 4*7*64 = 1792 (b, f-pair, k) combos, reduce to scalar.
__global__ __launch_bounds__(256) void finish_kernel(const float* __restrict__ gsum,
                                                     const float* __restrict__ gcnt,
                                                     float* __restrict__ out) {
    float total = 0.0f, nv = 0.0f;
    for (int idx = threadIdx.x; idx < NB * (NF - 1) * NK; idx += 256) {
        const int k = idx & 63;
        const int bfr = idx >> 6;
        const int b = bfr / (NF - 1);
        const int f = bfr % (NF - 1);
        const int bf0 = b * NF + f;
        if (k == 0) continue;
        const float c0 = gcnt[bf0 * NK + k];
        const float c1 = gcnt[(bf0 + 1) * NK + k];
        if (c0 > 0.0f && c1 > 0.0f) {
            const float r0 = 1.0f / c0, r1 = 1.0f / c1;
            float d = 0.0f;
            #pragma unroll
            for (int c = 0; c < NC; ++c) {
                const float m0 = gsum[(size_t)bf0 * (NK * NC) + k * NC + c] * r0;
                const float m1 = gsum[(size_t)(bf0 + 1) * (NK * NC) + k * NC + c] * r1;
                const float df = m0 - m1;
                d += df * df;
            }
            total += d;
            nv += 1.0f;
        }
    }
    const int lane = threadIdx.x & 63;
    const int wvi  = threadIdx.x >> 6;
    #pragma unroll
    for (int off = 32; off > 0; off >>= 1) {
        total += __shfl_down(total, off, 64);
        nv    += __shfl_down(nv, off, 64);
    }
    __shared__ float sT[4], sN[4];
    if (lane == 0) { sT[wvi] = total; sN[wvi] = nv; }
    __syncthreads();
    if (threadIdx.x == 0) {
        const float t = sT[0] + sT[1] + sT[2] + sT[3];
        const float n = sN[0] + sN[1] + sN[2] + sN[3];
        out[0] = (n > 0.0f) ? (t / n) : 0.0f;
    }
}

extern "C" void kernel_launch(void* const* d_in, const int* in_sizes, int n_in,
                              void* d_out, int out_size, void* d_ws, size_t ws_size,
                              hipStream_t stream) {
    const float* E = (const float*)d_in[0];   // embeddings (4,8,16,256,256) f32
    const int*   T = (const int*)d_in[1];     // track_ids  (4,8,1,256,256) i32
    float* out = (float*)d_out;

    float* part = (float*)d_ws;                          // [2048][1088] = 8.9 MB
    float* gsum = part + (size_t)(NBF * BPF) * PARTSZ;   // [32][64][16]
    float* gcnt = gsum + NBF * NK * NC;                  // [32][64]

    accum_mfma<<<NBF * BPF, 256, 0, stream>>>(E, T, part);
    reduce_kernel<<<(NBF * NK * NC + NBF * NK) / 256, 256, 0, stream>>>(part, gsum, gcnt);
    finish_kernel<<<1, 256, 0, stream>>>(gsum, gcnt, out);
}

// Round 8
// 207.491 us; speedup vs baseline: 2.1189x; 1.0297x over previous
//
#include <hip/hip_runtime.h>
#include <hip/hip_bf16.h>

// Problem constants: B=4, F=8, C=16, H=256, W=256, K=64
#define NB 4
#define NF 8
#define NC 16
#define NK 64
#define HW 65536              // H*W
#define NBF 32                // B*F
#define BPF 64                // blocks per frame (2048 blocks)
#define PPB (HW / BPF)        // 1024 pixels per block
#define PPW (PPB / 4)         // 256 pixels per wave
#define STEPS (PPW / 32)      // 8 K-steps of 32 pixels
#define PARTSZ 1088           // per-block partial: 1024 sums + 64 counts

typedef __attribute__((ext_vector_type(8))) short bf16x8;  // MFMA A/B frag (8 bf16)
typedef __attribute__((ext_vector_type(4))) float f32x4;   // MFMA C/D frag

__device__ __forceinline__ short f32_to_bf16_bits(float x) {
    union { float f; unsigned u; } v; v.f = x;
    unsigned r = v.u + 0x7FFFu + ((v.u >> 16) & 1u);   // round-nearest-even
    return (short)(r >> 16);
}

// Segment-sum via one-hot MFMA. Per wave: 32-pixel K-steps.
//   A (16x32, bf16): onehot[k - 16t][p]; rows = lane&15, k-slots mirrored with B.
//   B (32x16, bf16): data[p][c]; cols = lane&15 (channel plane), 8 px/lane.
//   C/D layout (verified m89/m91): col = lane&15, row = (lane>>4)*4 + reg.
// r8 change: DEEP PREFETCH — all 16 global float4 loads issued up-front into a
// statically-indexed register buffer (64 VGPR), consumed by a fully-unrolled
// compute loop. Tests the per-wave MLP-starvation theory (r3/r5/r7 all ~75us
// with <=2-4 outstanding loads/wave and every pipe <15% busy).
// NOTE: no min-waves launch_bounds — (256,8) caused scratch spills (r4).
__global__ __launch_bounds__(256) void accum_mfma(const float* __restrict__ E,
                                                  const int* __restrict__ T,
                                                  float* __restrict__ part) {  // [2048][PARTSZ]
    __shared__ int   sids[PPB];         // 4 KiB
    __shared__ float lsum[4][NK][NC];   // 16 KiB
    __shared__ float lcnt[4][NK];       // 1 KiB

    const int tid = threadIdx.x;
    const int wv  = tid >> 6;
    const int l   = tid & 63;
    const int col = l & 15;    // channel (B/C col) AND A row-within-tile
    const int grp = l >> 4;    // pixel-slot group

    const int bf    = blockIdx.x / BPF;
    const int chunk = blockIdx.x % BPF;

    // Stage this block's 1024 ids into LDS (one block-wide int4 load).
    *reinterpret_cast<int4*>(&sids[tid * 4]) =
        *reinterpret_cast<const int4*>(T + (size_t)bf * HW + chunk * PPB + tid * 4);

    const int base = chunk * PPB + wv * PPW + grp * 8;
    const float* Ep = E + ((size_t)bf * NC + col) * HW + base;
    const int* sip = &sids[wv * PPW + grp * 8];

    // Issue ALL data loads up-front: 16 outstanding float4 per wave.
    float4 dbuf[2 * STEPS];
    #pragma unroll
    for (int s = 0; s < STEPS; ++s) {
        dbuf[2 * s]     = *reinterpret_cast<const float4*>(Ep + s * 32);
        dbuf[2 * s + 1] = *reinterpret_cast<const float4*>(Ep + s * 32 + 4);
    }

    __syncthreads();   // ids visible (placed after load-issue so loads overlap)

    f32x4 accS[4], accC[4];
    #pragma unroll
    for (int t = 0; t < 4; ++t) { accS[t] = (f32x4){0,0,0,0}; accC[t] = (f32x4){0,0,0,0}; }

    // Constant ones-fragment: B[p][0] = 1.0 for all p -> counts land in col 0.
    bf16x8 bOnes;
    {
        const short ov = (col == 0) ? (short)0x3F80 : (short)0;
        #pragma unroll
        for (int j = 0; j < 8; ++j) bOnes[j] = ov;
    }

    #pragma unroll
    for (int s = 0; s < STEPS; ++s) {
        const int off = s * 32;
        const int4 i0 = *reinterpret_cast<const int4*>(sip + off);      // LDS broadcast
        const int4 i1 = *reinterpret_cast<const int4*>(sip + off + 4);  // LDS broadcast
        const float4 d0 = dbuf[2 * s];
        const float4 d1 = dbuf[2 * s + 1];

        const int   idv[8] = {i0.x, i0.y, i0.z, i0.w, i1.x, i1.y, i1.z, i1.w};
        const float dv[8]  = {d0.x, d0.y, d0.z, d0.w, d1.x, d1.y, d1.z, d1.w};

        bf16x8 bF;
        #pragma unroll
        for (int j = 0; j < 8; ++j) bF[j] = f32_to_bf16_bits(dv[j]);

        #pragma unroll
        for (int t = 0; t < 4; ++t) {
            const int ktar = t * 16 + col;
            bf16x8 aT;
            #pragma unroll
            for (int j = 0; j < 8; ++j) aT[j] = (idv[j] == ktar) ? (short)0x3F80 : (short)0;
            accS[t] = __builtin_amdgcn_mfma_f32_16x16x32_bf16(aT, bF,    accS[t], 0, 0, 0);
            accC[t] = __builtin_amdgcn_mfma_f32_16x16x32_bf16(aT, bOnes, accC[t], 0, 0, 0);
        }
    }

    // Cross-wave reduce in LDS, then plain coalesced stores of block partials.
    #pragma unroll
    for (int t = 0; t < 4; ++t) {
        #pragma unroll
        for (int j = 0; j < 4; ++j) {
            const int k = t * 16 + grp * 4 + j;   // C/D row mapping (m89)
            lsum[wv][k][col] = accS[t][j];
            if (col == 0) lcnt[wv][k] = accC[t][j];
        }
    }
    __syncthreads();

    float* pp = part + (size_t)blockIdx.x * PARTSZ;
    const float* lp = &lsum[0][0][0];
    for (int i = tid; i < NK * NC; i += 256) {
        pp[i] = lp[i] + lp[NK*NC + i] + lp[2*NK*NC + i] + lp[3*NK*NC + i];
    }
    if (tid < NK) {
        pp[NK * NC + tid] = lcnt[0][tid] + lcnt[1][tid] + lcnt[2][tid] + lcnt[3][tid];
    }
}

// Sum the 64 block-partials per frame, fixed order, no atomics.
// Grid: 136 blocks x 256 threads = 34816 = 32768 sum-elems + 2048 cnt-elems.
__global__ __launch_bounds__(256) void reduce_kernel(const float* __restrict__ part,
                                                     float* __restrict__ gsum,   // [bf][k][c]
                                                     float* __restrict__ gcnt) { // [bf][k]
    const int e = blockIdx.x * 256 + threadIdx.x;
    if (e < NBF * NK * NC) {
        const int bf = e >> 10;          // / 1024
        const int i  = e & 1023;
        const float* p = part + (size_t)(bf * BPF) * PARTSZ + i;
        float s = 0.0f;
        #pragma unroll 8
        for (int blk = 0; blk < BPF; ++blk) s += p[(size_t)blk * PARTSZ];
        gsum[e] = s;
    } else {
        const int e2 = e - NBF * NK * NC;
        const int bf = e2 >> 6;
        const int k  = e2 & 63;
        const float* p = part + (size_t)(bf * BPF) * PARTSZ + NK * NC + k;
        float s = 0.0f;
        #pragma unroll 8
        for (int blk = 0; blk < BPF; ++blk) s += p[(size_t)blk * PARTSZ];
        gcnt[e2] = s;
    }
}

// Single block: 4*7*64 = 1792 (b, f-pair, k) combos, reduce to scalar.
__global__ __launch_bounds__(256) void finish_kernel(const float* __restrict__ gsum,
                                                     const float* __restrict__ gcnt,
                                                     float* __restrict__ out) {
    float total = 0.0f, nv = 0.0f;
    for (int idx = threadIdx.x; idx < NB * (NF - 1) * NK; idx += 256) {
        const int k = idx & 63;
        const int bfr = idx >> 6;
        const int b = bfr / (NF - 1);
        const int f = bfr % (NF - 1);
        const int bf0 = b * NF + f;
        if (k == 0) continue;
        const float c0 = gcnt[bf0 * NK + k];
        const float c1 = gcnt[(bf0 + 1) * NK + k];
        if (c0 > 0.0f && c1 > 0.0f) {
            const float r0 = 1.0f / c0, r1 = 1.0f / c1;
            float d = 0.0f;
            #pragma unroll
            for (int c = 0; c < NC; ++c) {
                const float m0 = gsum[(size_t)bf0 * (NK * NC) + k * NC + c] * r0;
                const float m1 = gsum[(size_t)(bf0 + 1) * (NK * NC) + k * NC + c] * r1;
                const float df = m0 - m1;
                d += df * df;
            }
            total += d;
            nv += 1.0f;
        }
    }
    const int lane = threadIdx.x & 63;
    const int wvi  = threadIdx.x >> 6;
    #pragma unroll
    for (int off = 32; off > 0; off >>= 1) {
        total += __shfl_down(total, off, 64);
        nv    += __shfl_down(nv, off, 64);
    }
    __shared__ float sT[4], sN[4];
    if (lane == 0) { sT[wvi] = total; sN[wvi] = nv; }
    __syncthreads();
    if (threadIdx.x == 0) {
        const float t = sT[0] + sT[1] + sT[2] + sT[3];
        const float n = sN[0] + sN[1] + sN[2] + sN[3];
        out[0] = (n > 0.0f) ? (t / n) : 0.0f;
    }
}

extern "C" void kernel_launch(void* const* d_in, const int* in_sizes, int n_in,
                              void* d_out, int out_size, void* d_ws, size_t ws_size,
                              hipStream_t stream) {
    const float* E = (const float*)d_in[0];   // embeddings (4,8,16,256,256) f32
    const int*   T = (const int*)d_in[1];     // track_ids  (4,8,1,256,256) i32
    float* out = (float*)d_out;

    float* part = (float*)d_ws;                          // [2048][1088] = 8.9 MB
    float* gsum = part + (size_t)(NBF * BPF) * PARTSZ;   // [32][64][16]
    float* gcnt = gsum + NBF * NK * NC;                  // [32][64]

    accum_mfma<<<NBF * BPF, 256, 0, stream>>>(E, T, part);
    reduce_kernel<<<(NBF * NK * NC + NBF * NK) / 256, 256, 0, stream>>>(part, gsum, gcnt);
    finish_kernel<<<1, 256, 0, stream>>>(gsum, gcnt, out);
}